// Round 10
// baseline (117.168 us; speedup 1.0000x reference)
//
#include <hip/hip_runtime.h>

// Problem constants (from reference): A=5, B=2, K=5, C=13, H=W=256
constexpr int A_ = 5, B_ = 2, K_ = 5, C_ = 13, H_ = 256, W_ = 256;
constexpr int HW_ = H_ * W_;
constexpr int TILE = 32;
constexpr int REG = TILE + 1;            // 33 (tile + 1 halo for pass-2 taps)
constexpr int NPOS = REG * REG;          // 1089
constexpr int NT = 256;
constexpr int PPT = (NPOS + NT - 1) / NT; // 5 positions per thread
constexpr int NTILES = 64;               // 8x8 tiles of 32x32
constexpr int NBLK = NTILES * A_ * B_ * K_ * C_;  // 41600
constexpr int NXCD = 8;
constexpr int CHUNK = NBLK / NXCD;       // 5200 (exact)

// 8-byte vector load with 4-byte alignment guarantee (gfx950 unaligned
// global access is legal; compiler emits global_load_dwordx2)
typedef float float2u __attribute__((ext_vector_type(2), aligned(4)));

__global__ __launch_bounds__(NT)
void fafmimo_warp_kernel(const float* __restrict__ bevs,
                         const float* __restrict__ tm,
                         const int*   __restrict__ nat,
                         const int*   __restrict__ center_p,
                         float* __restrict__ out)
{
    // XCD-contiguity swizzle: consecutive hardware dispatch round-robins
    // XCDs (n % 8 = xcd), so give XCD x the contiguous work range
    // [x*CHUNK, (x+1)*CHUNK). Work order: tile fastest within (abk, ch)
    // -> all 64 tiles re-reading one 256KB channel slice share one L2.
    const int n = blockIdx.x;
    const int w = (n & 7) * CHUNK + (n >> 3);
    const int tileIdx = w & 63;
    const int rest    = w >> 6;          // 0..649
    const int ch      = rest % C_;
    const int abk     = rest / C_;       // 0..49 == (a*B+b)*K + k

    const int a   = abk / (B_ * K_);
    const int rem = abk % (B_ * K_);
    const int b   = rem / K_;
    const int k   = rem % K_;

    const int center  = center_p[0];
    const int n_agent = nat[b * A_ + center];
    const bool masked = (a < n_agent) && ((a != center) || (k == K_ - 1));

    const int th0 = (tileIdx >> 3) * TILE;
    const int tw0 = (tileIdx & 7) * TILE;

    const int tid = threadIdx.x;
    const int rr  = tid >> 3;            // output row within tile, 0..31
    const int cg  = (tid & 7) << 2;      // output col group (float4), 0..28

    const float* __restrict__ img = bevs + (size_t)(abk * C_ + ch) * HW_;
    float*       __restrict__ o   = out  + (size_t)(abk * C_ + ch) * HW_;
    const int off = (th0 + rr) * W_ + tw0 + cg;

    if (!masked) {
        // straight copy of this channel tile (float4, coalesced)
        const float4 v = *reinterpret_cast<const float4*>(img + off);
        *reinterpret_cast<float4*>(o + off) = v;
        return;
    }

    // --- per-image transform params (trans_mats shape (A,K,B,4,4)) ---
    const int tb = ((a * K_ + k) * B_ + b) * 16;
    const float t00 = tm[tb + 0], t01 = tm[tb + 1], t03 = tm[tb + 3];
    const float t10 = tm[tb + 4], t11 = tm[tb + 5], t13 = tm[tb + 7];

    // Pass-2 (translation) in pixel units
    const float dx = 4.0f * t03;
    const float dy = -4.0f * t13;
    const float fxf = floorf(dx), fyf = floorf(dy);
    const int   fx = (int)fxf,    fy = (int)fyf;
    const float wx2 = dx - fxf,   wy2 = dy - fyf;
    const float w00 = (1.0f - wx2) * (1.0f - wy2);
    const float w01 = wx2 * (1.0f - wy2);
    const float w10 = (1.0f - wx2) * wy2;
    const float w11 = wx2 * wy2;

    // source coords: ix = t00*gx + t01*gy + cxk (verified formula R3-R9)
    const float cxk = 127.5f - 127.5f * (t00 + t01);
    const float cyk = 127.5f - 127.5f * (t10 + t11);

    // Adaptive traversal: walk the S1 region in the direction with the
    // smaller per-lane source-row step (fewer unique 64B lines per wave).
    const bool rowMajor = fabsf(t10) <= fabsf(t01);

    __shared__ float lds[NPOS];
    __shared__ int   anyflag;
    if (tid == 0) anyflag = 0;

    // --- pass-1 taps for the 33x33 S1 region ---
    int   sidx[PPT], oA[PPT], oB[PPT];
    float aAx[PPT], aAy[PPT], aBx[PPT], aBy[PPT];
    bool  hasAny = false;
    #pragma unroll
    for (int it = 0; it < PPT; ++it) {
        const int p = tid + it * NT;
        const int u = p / REG;
        const int v = p - u * REG;
        const int pr = rowMajor ? u : v;
        const int pc = rowMajor ? v : u;
        const int gyp = th0 + fy + pr;
        const int gxp = tw0 + fx + pc;
        const bool inreg = (p < NPOS) &&
                           (gyp >= 0) && (gyp < H_) && (gxp >= 0) && (gxp < W_);
        const float ix = fmaf(t00, (float)gxp, fmaf(t01, (float)gyp, cxk));
        const float iy = fmaf(t10, (float)gxp, fmaf(t11, (float)gyp, cyk));
        const float x0f = floorf(ix), y0f = floorf(iy);
        const float wx = ix - x0f,    wy = iy - y0f;
        const int x0 = (int)x0f, y0 = (int)y0f;
        const int x1 = x0 + 1,   y1 = y0 + 1;
        const bool vx0 = (x0 >= 0) && (x0 < W_);
        const bool vx1 = (x1 >= 0) && (x1 < W_);
        const bool vy0 = (y0 >= 0) && (y0 < H_);
        const bool vy1 = (y1 >= 0) && (y1 < H_);
        const int cx0 = min(max(x0, 0), W_ - 1);
        const int cx1 = min(max(x1, 0), W_ - 1);
        const int cy0 = min(max(y0, 0), H_ - 1);
        const int cy1 = min(max(y1, 0), H_ - 1);
        const float m = inreg ? 1.0f : 0.0f;
        const float q0 = (1.0f - wx) * (1.0f - wy) * ((vx0 && vy0) ? m : 0.0f);
        const float q1 = wx * (1.0f - wy)          * ((vx1 && vy0) ? m : 0.0f);
        const float q2 = (1.0f - wx) * wy          * ((vx0 && vy1) ? m : 0.0f);
        const float q3 = wx * wy                   * ((vx1 && vy1) ? m : 0.0f);

        // fold x0/x1 taps of each source row into one 8B pair load at xs
        const int xs = min(max(x0, 0), W_ - 2);
        oA[it] = cy0 * W_ + xs;
        oB[it] = cy1 * W_ + xs;
        aAx[it] = (cx0 == xs     ? q0 : 0.0f) + (cx1 == xs     ? q1 : 0.0f);
        aAy[it] = (cx0 == xs + 1 ? q0 : 0.0f) + (cx1 == xs + 1 ? q1 : 0.0f);
        aBx[it] = (cx0 == xs     ? q2 : 0.0f) + (cx1 == xs     ? q3 : 0.0f);
        aBy[it] = (cx0 == xs + 1 ? q2 : 0.0f) + (cx1 == xs + 1 ? q3 : 0.0f);
        sidx[it] = (p < NPOS) ? (pr * REG + pc) : -1;
        hasAny |= (aAx[it] != 0.f) || (aAy[it] != 0.f) ||
                  (aBx[it] != 0.f) || (aBy[it] != 0.f);
    }

    __syncthreads();
    if (hasAny) anyflag = 1;             // benign race: all writers store 1
    __syncthreads();

    if (!anyflag) {
        // whole S1 region has zero weight -> this channel tile is zeros
        *reinterpret_cast<float4*>(o + off) = make_float4(0.f, 0.f, 0.f, 0.f);
        return;
    }

    // pass 1: predicated paired gathers into LDS (<=10 loads per thread)
    #pragma unroll
    for (int it = 0; it < PPT; ++it) {
        float s = 0.0f;
        if (aAx[it] != 0.f || aAy[it] != 0.f) {
            const float2u v = *reinterpret_cast<const float2u*>(img + oA[it]);
            s += aAx[it] * v.x + aAy[it] * v.y;
        }
        if (aBx[it] != 0.f || aBy[it] != 0.f) {
            const float2u v = *reinterpret_cast<const float2u*>(img + oB[it]);
            s += aBx[it] * v.x + aBy[it] * v.y;
        }
        if (sidx[it] >= 0) lds[sidx[it]] = s;
    }
    __syncthreads();

    // pass 2: constant-weight 2x2 blend from LDS, 4 outputs per thread
    const float* Lr0 = lds + rr * REG + cg;
    const float* Lr1 = Lr0 + REG;
    const float l0 = Lr0[0], l1 = Lr0[1], l2 = Lr0[2], l3 = Lr0[3], l4 = Lr0[4];
    const float m0 = Lr1[0], m1 = Lr1[1], m2 = Lr1[2], m3 = Lr1[3], m4 = Lr1[4];
    float4 v;
    v.x = w00 * l0 + w01 * l1 + w10 * m0 + w11 * m1;
    v.y = w00 * l1 + w01 * l2 + w10 * m1 + w11 * m2;
    v.z = w00 * l2 + w01 * l3 + w10 * m2 + w11 * m3;
    v.w = w00 * l3 + w01 * l4 + w10 * m3 + w11 * m4;
    *reinterpret_cast<float4*>(o + off) = v;
}

extern "C" void kernel_launch(void* const* d_in, const int* in_sizes, int n_in,
                              void* d_out, int out_size, void* d_ws, size_t ws_size,
                              hipStream_t stream) {
    const float* bevs   = (const float*)d_in[0];
    const float* tm     = (const float*)d_in[1];
    const int*   nat    = (const int*)d_in[2];
    const int*   center = (const int*)d_in[4];
    float* out = (float*)d_out;

    dim3 grid(NBLK);
    dim3 block(NT);
    fafmimo_warp_kernel<<<grid, block, 0, stream>>>(bevs, tm, nat, center, out);
}

// Round 11
// 78.896 us; speedup vs baseline: 1.4851x; 1.4851x over previous
//
#include <hip/hip_runtime.h>

// Problem constants (from reference): A=5, B=2, K=5, C=13, H=W=256
constexpr int A_ = 5, B_ = 2, K_ = 5, C_ = 13, H_ = 256, W_ = 256;
constexpr int HW_ = H_ * W_;
constexpr int TILE = 32;
constexpr int REG = TILE + 1;            // 33 (tile + 1 halo for pass-2 taps)
constexpr int NPOS = REG * REG;          // 1089
constexpr int NT = 256;
constexpr int PPT = (NPOS + NT - 1) / NT; // 5 positions per thread
constexpr int NTILES = 64;               // 8x8 tiles of 32x32
constexpr int NSLICE = A_ * B_ * K_ * C_;          // 650 (abk,ch) slices
constexpr int NBLK = NTILES * NSLICE;              // 41600
constexpr int NXCD = 8;
constexpr int GMAIN = (NSLICE / NXCD) * NXCD;      // 648 slices in main part
constexpr int NMAIN = GMAIN * NTILES;              // 41472 blocks

// 8-byte vector load with 4-byte alignment guarantee (gfx950 unaligned
// global access is legal; compiler emits global_load_dwordx2)
typedef float float2u __attribute__((ext_vector_type(2), aligned(4)));

__global__ __launch_bounds__(NT)
void fafmimo_warp_kernel(const float* __restrict__ bevs,
                         const float* __restrict__ tm,
                         const int*   __restrict__ nat,
                         const int*   __restrict__ center_p,
                         float* __restrict__ out)
{
    // Balanced XCD-locality swizzle: hardware sends block n to XCD n%8.
    // Map so slice g's 64 tiles all land on XCD g%8 (slice L2-resident),
    // while slices round-robin across XCDs (heavy/light work interleaved
    // in time on every XCD -> no R10-style tail imbalance).
    const int n = blockIdx.x;
    int g, t;
    if (n < NMAIN) {
        const int x = n & 7;             // XCD
        const int s = n >> 3;            // slot within XCD
        g = ((s >> 6) << 3) + x;         // slice = 8*(slot/64) + xcd
        t = s & 63;                      // tile within slice
    } else {
        const int m = n - NMAIN;         // 128-block tail: slices 648,649
        g = GMAIN + (m >> 6);
        t = m & 63;
    }
    const int tileIdx = t;
    const int ch      = g % C_;
    const int abk     = g / C_;          // 0..49 == (a*B+b)*K + k

    const int a   = abk / (B_ * K_);
    const int rem = abk % (B_ * K_);
    const int b   = rem / K_;
    const int k   = rem % K_;

    const int center  = center_p[0];
    const int n_agent = nat[b * A_ + center];
    const bool masked = (a < n_agent) && ((a != center) || (k == K_ - 1));

    const int th0 = (tileIdx >> 3) * TILE;
    const int tw0 = (tileIdx & 7) * TILE;

    const int tid = threadIdx.x;
    const int rr  = tid >> 3;            // output row within tile, 0..31
    const int cg  = (tid & 7) << 2;      // output col group (float4), 0..28

    const float* __restrict__ img = bevs + (size_t)(abk * C_ + ch) * HW_;
    float*       __restrict__ o   = out  + (size_t)(abk * C_ + ch) * HW_;
    const int off = (th0 + rr) * W_ + tw0 + cg;

    if (!masked) {
        // straight copy of this channel tile (float4, coalesced)
        const float4 v = *reinterpret_cast<const float4*>(img + off);
        *reinterpret_cast<float4*>(o + off) = v;
        return;
    }

    // --- per-image transform params (trans_mats shape (A,K,B,4,4)) ---
    const int tb = ((a * K_ + k) * B_ + b) * 16;
    const float t00 = tm[tb + 0], t01 = tm[tb + 1], t03 = tm[tb + 3];
    const float t10 = tm[tb + 4], t11 = tm[tb + 5], t13 = tm[tb + 7];

    // Pass-2 (translation) in pixel units
    const float dx = 4.0f * t03;
    const float dy = -4.0f * t13;
    const float fxf = floorf(dx), fyf = floorf(dy);
    const int   fx = (int)fxf,    fy = (int)fyf;
    const float wx2 = dx - fxf,   wy2 = dy - fyf;
    const float w00 = (1.0f - wx2) * (1.0f - wy2);
    const float w01 = wx2 * (1.0f - wy2);
    const float w10 = (1.0f - wx2) * wy2;
    const float w11 = wx2 * wy2;

    // source coords: ix = t00*gx + t01*gy + cxk (verified formula R3-R10)
    const float cxk = 127.5f - 127.5f * (t00 + t01);
    const float cyk = 127.5f - 127.5f * (t10 + t11);

    // Adaptive traversal: walk the S1 region in the direction with the
    // smaller per-lane source-row step (fewer unique 64B lines per wave).
    const bool rowMajor = fabsf(t10) <= fabsf(t01);

    __shared__ float lds[NPOS];
    __shared__ int   anyflag;
    if (tid == 0) anyflag = 0;

    // --- pass-1 taps for the 33x33 S1 region ---
    int   sidx[PPT], oA[PPT], oB[PPT];
    float aAx[PPT], aAy[PPT], aBx[PPT], aBy[PPT];
    bool  hasAny = false;
    #pragma unroll
    for (int it = 0; it < PPT; ++it) {
        const int p = tid + it * NT;
        const int u = p / REG;
        const int v = p - u * REG;
        const int pr = rowMajor ? u : v;
        const int pc = rowMajor ? v : u;
        const int gyp = th0 + fy + pr;
        const int gxp = tw0 + fx + pc;
        const bool inreg = (p < NPOS) &&
                           (gyp >= 0) && (gyp < H_) && (gxp >= 0) && (gxp < W_);
        const float ix = fmaf(t00, (float)gxp, fmaf(t01, (float)gyp, cxk));
        const float iy = fmaf(t10, (float)gxp, fmaf(t11, (float)gyp, cyk));
        const float x0f = floorf(ix), y0f = floorf(iy);
        const float wx = ix - x0f,    wy = iy - y0f;
        const int x0 = (int)x0f, y0 = (int)y0f;
        const int x1 = x0 + 1,   y1 = y0 + 1;
        const bool vx0 = (x0 >= 0) && (x0 < W_);
        const bool vx1 = (x1 >= 0) && (x1 < W_);
        const bool vy0 = (y0 >= 0) && (y0 < H_);
        const bool vy1 = (y1 >= 0) && (y1 < H_);
        const int cx0 = min(max(x0, 0), W_ - 1);
        const int cx1 = min(max(x1, 0), W_ - 1);
        const int cy0 = min(max(y0, 0), H_ - 1);
        const int cy1 = min(max(y1, 0), H_ - 1);
        const float m = inreg ? 1.0f : 0.0f;
        const float q0 = (1.0f - wx) * (1.0f - wy) * ((vx0 && vy0) ? m : 0.0f);
        const float q1 = wx * (1.0f - wy)          * ((vx1 && vy0) ? m : 0.0f);
        const float q2 = (1.0f - wx) * wy          * ((vx0 && vy1) ? m : 0.0f);
        const float q3 = wx * wy                   * ((vx1 && vy1) ? m : 0.0f);

        // fold x0/x1 taps of each source row into one 8B pair load at xs
        const int xs = min(max(x0, 0), W_ - 2);
        oA[it] = cy0 * W_ + xs;
        oB[it] = cy1 * W_ + xs;
        aAx[it] = (cx0 == xs     ? q0 : 0.0f) + (cx1 == xs     ? q1 : 0.0f);
        aAy[it] = (cx0 == xs + 1 ? q0 : 0.0f) + (cx1 == xs + 1 ? q1 : 0.0f);
        aBx[it] = (cx0 == xs     ? q2 : 0.0f) + (cx1 == xs     ? q3 : 0.0f);
        aBy[it] = (cx0 == xs + 1 ? q2 : 0.0f) + (cx1 == xs + 1 ? q3 : 0.0f);
        sidx[it] = (p < NPOS) ? (pr * REG + pc) : -1;
        hasAny |= (aAx[it] != 0.f) || (aAy[it] != 0.f) ||
                  (aBx[it] != 0.f) || (aBy[it] != 0.f);
    }

    __syncthreads();
    if (hasAny) anyflag = 1;             // benign race: all writers store 1
    __syncthreads();

    if (!anyflag) {
        // whole S1 region has zero weight -> this channel tile is zeros
        *reinterpret_cast<float4*>(o + off) = make_float4(0.f, 0.f, 0.f, 0.f);
        return;
    }

    // pass 1: predicated paired gathers into LDS (<=10 loads per thread)
    #pragma unroll
    for (int it = 0; it < PPT; ++it) {
        float s = 0.0f;
        if (aAx[it] != 0.f || aAy[it] != 0.f) {
            const float2u v = *reinterpret_cast<const float2u*>(img + oA[it]);
            s += aAx[it] * v.x + aAy[it] * v.y;
        }
        if (aBx[it] != 0.f || aBy[it] != 0.f) {
            const float2u v = *reinterpret_cast<const float2u*>(img + oB[it]);
            s += aBx[it] * v.x + aBy[it] * v.y;
        }
        if (sidx[it] >= 0) lds[sidx[it]] = s;
    }
    __syncthreads();

    // pass 2: constant-weight 2x2 blend from LDS, 4 outputs per thread
    const float* Lr0 = lds + rr * REG + cg;
    const float* Lr1 = Lr0 + REG;
    const float l0 = Lr0[0], l1 = Lr0[1], l2 = Lr0[2], l3 = Lr0[3], l4 = Lr0[4];
    const float m0 = Lr1[0], m1 = Lr1[1], m2 = Lr1[2], m3 = Lr1[3], m4 = Lr1[4];
    float4 v;
    v.x = w00 * l0 + w01 * l1 + w10 * m0 + w11 * m1;
    v.y = w00 * l1 + w01 * l2 + w10 * m1 + w11 * m2;
    v.z = w00 * l2 + w01 * l3 + w10 * m2 + w11 * m3;
    v.w = w00 * l3 + w01 * l4 + w10 * m3 + w11 * m4;
    *reinterpret_cast<float4*>(o + off) = v;
}

extern "C" void kernel_launch(void* const* d_in, const int* in_sizes, int n_in,
                              void* d_out, int out_size, void* d_ws, size_t ws_size,
                              hipStream_t stream) {
    const float* bevs   = (const float*)d_in[0];
    const float* tm     = (const float*)d_in[1];
    const int*   nat    = (const int*)d_in[2];
    const int*   center = (const int*)d_in[4];
    float* out = (float*)d_out;

    dim3 grid(NBLK);
    dim3 block(NT);
    fafmimo_warp_kernel<<<grid, block, 0, stream>>>(bevs, tm, nat, center, out);
}

// Round 13
// 68.038 us; speedup vs baseline: 1.7221x; 1.1596x over previous
//
#include <hip/hip_runtime.h>

// Problem constants (from reference): A=5, B=2, K=5, C=13, H=W=256
constexpr int A_ = 5, B_ = 2, K_ = 5, C_ = 13, H_ = 256, W_ = 256;
constexpr int HW_ = H_ * W_;
constexpr int TILE = 32;
constexpr int REG = TILE + 1;            // 33 (tile + 1 halo for pass-2 taps)
constexpr int NPOS = REG * REG;          // 1089
constexpr int NT = 256;
constexpr int PPT = (NPOS + NT - 1) / NT; // 5 positions per thread
constexpr int NTILES = 64;               // 8x8 tiles of 32x32
constexpr int NSLICE = A_ * B_ * K_ * C_;          // 650 (abk,ch) slices
constexpr int NBLK = NTILES * NSLICE;              // 41600
constexpr int NXCD = 8;
constexpr int GMAIN = (NSLICE / NXCD) * NXCD;      // 648 slices in main part
constexpr int NMAIN = GMAIN * NTILES;              // 41472 blocks

// clang ext vectors (HIP_vector_type float4 is NOT accepted by
// __builtin_nontemporal_*; ext_vector_type is)
typedef float float2u __attribute__((ext_vector_type(2), aligned(4)));
typedef float float4e __attribute__((ext_vector_type(4), aligned(16)));

__global__ __launch_bounds__(NT)
void fafmimo_warp_kernel(const float* __restrict__ bevs,
                         const float* __restrict__ tm,
                         const int*   __restrict__ nat,
                         const int*   __restrict__ center_p,
                         float* __restrict__ out)
{
    // Balanced XCD-locality swizzle (R11, +8.2 us): hardware sends block n
    // to XCD n%8. Slice g's 64 tiles all land on XCD g%8 (slice stays
    // L2-resident for its 4x tap re-reads), slices round-robin across
    // XCDs (heavy/light interleaved in time -> no tail imbalance).
    const int n = blockIdx.x;
    int g, t;
    if (n < NMAIN) {
        const int x = n & 7;             // XCD
        const int s = n >> 3;            // slot within XCD
        g = ((s >> 6) << 3) + x;         // slice = 8*(slot/64) + xcd
        t = s & 63;                      // tile within slice
    } else {
        const int m = n - NMAIN;         // 128-block tail: slices 648,649
        g = GMAIN + (m >> 6);
        t = m & 63;
    }
    const int tileIdx = t;
    const int ch      = g % C_;
    const int abk     = g / C_;          // 0..49 == (a*B+b)*K + k

    const int a   = abk / (B_ * K_);
    const int rem = abk % (B_ * K_);
    const int b   = rem / K_;
    const int k   = rem % K_;

    const int center  = center_p[0];
    const int n_agent = nat[b * A_ + center];
    const bool masked = (a < n_agent) && ((a != center) || (k == K_ - 1));

    const int th0 = (tileIdx >> 3) * TILE;
    const int tw0 = (tileIdx & 7) * TILE;

    const int tid = threadIdx.x;
    const int rr  = tid >> 3;            // output row within tile, 0..31
    const int cg  = (tid & 7) << 2;      // output col group (float4), 0..28

    const float* __restrict__ img = bevs + (size_t)(abk * C_ + ch) * HW_;
    float*       __restrict__ o   = out  + (size_t)(abk * C_ + ch) * HW_;
    const int off = (th0 + rr) * W_ + tw0 + cg;

    if (!masked) {
        // copy path: read-once data, never gathered -> non-temporal both
        // ways (don't evict gather taps from L2)
        const float4e v = __builtin_nontemporal_load(
            reinterpret_cast<const float4e*>(img + off));
        __builtin_nontemporal_store(v, reinterpret_cast<float4e*>(o + off));
        return;
    }

    // --- per-image transform params (trans_mats shape (A,K,B,4,4)) ---
    const int tb = ((a * K_ + k) * B_ + b) * 16;
    const float t00 = tm[tb + 0], t01 = tm[tb + 1], t03 = tm[tb + 3];
    const float t10 = tm[tb + 4], t11 = tm[tb + 5], t13 = tm[tb + 7];

    // Pass-2 (translation) in pixel units
    const float dx = 4.0f * t03;
    const float dy = -4.0f * t13;
    const float fxf = floorf(dx), fyf = floorf(dy);
    const int   fx = (int)fxf,    fy = (int)fyf;
    const float wx2 = dx - fxf,   wy2 = dy - fyf;
    const float w00 = (1.0f - wx2) * (1.0f - wy2);
    const float w01 = wx2 * (1.0f - wy2);
    const float w10 = (1.0f - wx2) * wy2;
    const float w11 = wx2 * wy2;

    // source coords: ix = t00*gx + t01*gy + cxk (verified formula R3-R11)
    const float cxk = 127.5f - 127.5f * (t00 + t01);
    const float cyk = 127.5f - 127.5f * (t10 + t11);

    // Adaptive traversal: walk the S1 region in the direction with the
    // smaller per-lane source-row step (fewer unique 64B lines per wave).
    const bool rowMajor = fabsf(t10) <= fabsf(t01);

    __shared__ float lds[NPOS];

    // --- pass-1 taps for the 33x33 S1 region ---
    int   sidx[PPT], oA[PPT], oB[PPT];
    float aAx[PPT], aAy[PPT], aBx[PPT], aBy[PPT];
    #pragma unroll
    for (int it = 0; it < PPT; ++it) {
        const int p = tid + it * NT;
        const int u = p / REG;
        const int v = p - u * REG;
        const int pr = rowMajor ? u : v;
        const int pc = rowMajor ? v : u;
        const int gyp = th0 + fy + pr;
        const int gxp = tw0 + fx + pc;
        const bool inreg = (p < NPOS) &&
                           (gyp >= 0) && (gyp < H_) && (gxp >= 0) && (gxp < W_);
        const float ix = fmaf(t00, (float)gxp, fmaf(t01, (float)gyp, cxk));
        const float iy = fmaf(t10, (float)gxp, fmaf(t11, (float)gyp, cyk));
        const float x0f = floorf(ix), y0f = floorf(iy);
        const float wx = ix - x0f,    wy = iy - y0f;
        const int x0 = (int)x0f, y0 = (int)y0f;
        const int x1 = x0 + 1,   y1 = y0 + 1;
        const bool vx0 = (x0 >= 0) && (x0 < W_);
        const bool vx1 = (x1 >= 0) && (x1 < W_);
        const bool vy0 = (y0 >= 0) && (y0 < H_);
        const bool vy1 = (y1 >= 0) && (y1 < H_);
        const int cx0 = min(max(x0, 0), W_ - 1);
        const int cx1 = min(max(x1, 0), W_ - 1);
        const int cy0 = min(max(y0, 0), H_ - 1);
        const int cy1 = min(max(y1, 0), H_ - 1);
        const float m = inreg ? 1.0f : 0.0f;
        const float q0 = (1.0f - wx) * (1.0f - wy) * ((vx0 && vy0) ? m : 0.0f);
        const float q1 = wx * (1.0f - wy)          * ((vx1 && vy0) ? m : 0.0f);
        const float q2 = (1.0f - wx) * wy          * ((vx0 && vy1) ? m : 0.0f);
        const float q3 = wx * wy                   * ((vx1 && vy1) ? m : 0.0f);

        // fold x0/x1 taps of each source row into one 8B pair load at xs
        const int xs = min(max(x0, 0), W_ - 2);
        oA[it] = cy0 * W_ + xs;
        oB[it] = cy1 * W_ + xs;
        aAx[it] = (cx0 == xs     ? q0 : 0.0f) + (cx1 == xs     ? q1 : 0.0f);
        aAy[it] = (cx0 == xs + 1 ? q0 : 0.0f) + (cx1 == xs + 1 ? q1 : 0.0f);
        aBx[it] = (cx0 == xs     ? q2 : 0.0f) + (cx1 == xs     ? q3 : 0.0f);
        aBy[it] = (cx0 == xs + 1 ? q2 : 0.0f) + (cx1 == xs + 1 ? q3 : 0.0f);
        sidx[it] = (p < NPOS) ? (pr * REG + pc) : -1;
    }

    // pass 1: predicated paired gathers into LDS (<=10 loads per thread;
    // fully-OOB lanes issue no memory transactions at all)
    #pragma unroll
    for (int it = 0; it < PPT; ++it) {
        float s = 0.0f;
        if (aAx[it] != 0.f || aAy[it] != 0.f) {
            const float2u v = *reinterpret_cast<const float2u*>(img + oA[it]);
            s += aAx[it] * v.x + aAy[it] * v.y;
        }
        if (aBx[it] != 0.f || aBy[it] != 0.f) {
            const float2u v = *reinterpret_cast<const float2u*>(img + oB[it]);
            s += aBx[it] * v.x + aBy[it] * v.y;
        }
        if (sidx[it] >= 0) lds[sidx[it]] = s;
    }
    __syncthreads();

    // pass 2: constant-weight 2x2 blend from LDS, 4 outputs per thread
    const float* Lr0 = lds + rr * REG + cg;
    const float* Lr1 = Lr0 + REG;
    const float l0 = Lr0[0], l1 = Lr0[1], l2 = Lr0[2], l3 = Lr0[3], l4 = Lr0[4];
    const float m0 = Lr1[0], m1 = Lr1[1], m2 = Lr1[2], m3 = Lr1[3], m4 = Lr1[4];
    float4e v;
    v.x = w00 * l0 + w01 * l1 + w10 * m0 + w11 * m1;
    v.y = w00 * l1 + w01 * l2 + w10 * m1 + w11 * m2;
    v.z = w00 * l2 + w01 * l3 + w10 * m2 + w11 * m3;
    v.w = w00 * l3 + w01 * l4 + w10 * m3 + w11 * m4;
    __builtin_nontemporal_store(v, reinterpret_cast<float4e*>(o + off));
}

extern "C" void kernel_launch(void* const* d_in, const int* in_sizes, int n_in,
                              void* d_out, int out_size, void* d_ws, size_t ws_size,
                              hipStream_t stream) {
    const float* bevs   = (const float*)d_in[0];
    const float* tm     = (const float*)d_in[1];
    const int*   nat    = (const int*)d_in[2];
    const int*   center = (const int*)d_in[4];
    float* out = (float*)d_out;

    dim3 grid(NBLK);
    dim3 block(NT);
    fafmimo_warp_kernel<<<grid, block, 0, stream>>>(bevs, tm, nat, center, out);
}

// Round 14
// 66.250 us; speedup vs baseline: 1.7686x; 1.0270x over previous
//
#include <hip/hip_runtime.h>

// Problem constants (from reference): A=5, B=2, K=5, C=13, H=W=256
constexpr int A_ = 5, B_ = 2, K_ = 5, C_ = 13, H_ = 256, W_ = 256;
constexpr int HW_ = H_ * W_;
constexpr int TILE = 32;
constexpr int REG = TILE + 1;            // 33 (tile + 1 halo for pass-2 taps)
constexpr int NPOS = REG * REG;          // 1089
constexpr int NT = 256;
constexpr int PPT = (NPOS + NT - 1) / NT; // 5 positions per thread
constexpr int NTILES = 64;               // 8x8 tiles of 32x32
constexpr int NSLICE = A_ * B_ * K_ * C_;          // 650 (abk,ch) slices
constexpr int NBLK = NTILES * NSLICE;              // 41600
constexpr int NXCD = 8;
constexpr int GMAIN = (NSLICE / NXCD) * NXCD;      // 648 slices in main part
constexpr int NMAIN = GMAIN * NTILES;              // 41472 blocks

// clang ext vectors (HIP_vector_type float4 is NOT accepted by
// __builtin_nontemporal_*; ext_vector_type is)
typedef float float2u __attribute__((ext_vector_type(2), aligned(4)));
typedef float float4e __attribute__((ext_vector_type(4), aligned(16)));

__global__ __launch_bounds__(NT)
void fafmimo_warp_kernel(const float* __restrict__ bevs,
                         const float* __restrict__ tm,
                         const int*   __restrict__ nat,
                         const int*   __restrict__ center_p,
                         float* __restrict__ out)
{
    // Balanced XCD-locality swizzle (R11, +8.2 us): hardware sends block n
    // to XCD n%8. Slice g's 64 tiles all land on XCD g%8 (slice stays
    // L2-resident for its 4x tap re-reads), slices round-robin across
    // XCDs (heavy/light interleaved in time -> no tail imbalance).
    const int n = blockIdx.x;
    int g, t;
    if (n < NMAIN) {
        const int x = n & 7;             // XCD
        const int s = n >> 3;            // slot within XCD
        g = ((s >> 6) << 3) + x;         // slice = 8*(slot/64) + xcd
        t = s & 63;                      // tile within slice
    } else {
        const int m = n - NMAIN;         // 128-block tail: slices 648,649
        g = GMAIN + (m >> 6);
        t = m & 63;
    }
    const int tileIdx = t;
    const int ch      = g % C_;
    const int abk     = g / C_;          // 0..49 == (a*B+b)*K + k

    const int a   = abk / (B_ * K_);
    const int rem = abk % (B_ * K_);
    const int b   = rem / K_;
    const int k   = rem % K_;

    const int center  = center_p[0];
    const int n_agent = nat[b * A_ + center];
    const bool masked = (a < n_agent) && ((a != center) || (k == K_ - 1));

    const int th0 = (tileIdx >> 3) * TILE;
    const int tw0 = (tileIdx & 7) * TILE;

    const int tid = threadIdx.x;
    const int rr  = tid >> 3;            // output row within tile, 0..31
    const int cg  = (tid & 7) << 2;      // output col group (float4), 0..28

    const float* __restrict__ img = bevs + (size_t)(abk * C_ + ch) * HW_;
    float*       __restrict__ o   = out  + (size_t)(abk * C_ + ch) * HW_;
    const int off = (th0 + rr) * W_ + tw0 + cg;

    if (!masked) {
        // copy path: read-once data, never gathered -> non-temporal both
        // ways (don't evict gather taps from L2)
        const float4e v = __builtin_nontemporal_load(
            reinterpret_cast<const float4e*>(img + off));
        __builtin_nontemporal_store(v, reinterpret_cast<float4e*>(o + off));
        return;
    }

    // --- per-image transform params (trans_mats shape (A,K,B,4,4)) ---
    const int tb = ((a * K_ + k) * B_ + b) * 16;
    const float t00 = tm[tb + 0], t01 = tm[tb + 1], t03 = tm[tb + 3];
    const float t10 = tm[tb + 4], t11 = tm[tb + 5], t13 = tm[tb + 7];

    // Pass-2 (translation) in pixel units
    const float dx = 4.0f * t03;
    const float dy = -4.0f * t13;
    const float fxf = floorf(dx), fyf = floorf(dy);
    const int   fx = (int)fxf,    fy = (int)fyf;
    const float wx2 = dx - fxf,   wy2 = dy - fyf;
    const float w00 = (1.0f - wx2) * (1.0f - wy2);
    const float w01 = wx2 * (1.0f - wy2);
    const float w10 = (1.0f - wx2) * wy2;
    const float w11 = wx2 * wy2;

    // source coords: ix = t00*gx + t01*gy + cxk (verified formula R3-R13)
    const float cxk = 127.5f - 127.5f * (t00 + t01);
    const float cyk = 127.5f - 127.5f * (t10 + t11);

    // Adaptive traversal: walk the S1 region in the direction with the
    // smaller per-lane source-row step (fewer unique 64B lines per wave).
    const bool rowMajor = fabsf(t10) <= fabsf(t01);

    __shared__ float lds[NPOS];

    // --- pass-1 taps for the 33x33 S1 region ---
    int   sidx[PPT], oA[PPT], oB[PPT];
    float aAx[PPT], aAy[PPT], aBx[PPT], aBy[PPT];
    #pragma unroll
    for (int it = 0; it < PPT; ++it) {
        const int p = tid + it * NT;
        const int u = p / REG;
        const int v = p - u * REG;
        const int pr = rowMajor ? u : v;
        const int pc = rowMajor ? v : u;
        const int gyp = th0 + fy + pr;
        const int gxp = tw0 + fx + pc;
        const bool inreg = (p < NPOS) &&
                           (gyp >= 0) && (gyp < H_) && (gxp >= 0) && (gxp < W_);
        const float ix = fmaf(t00, (float)gxp, fmaf(t01, (float)gyp, cxk));
        const float iy = fmaf(t10, (float)gxp, fmaf(t11, (float)gyp, cyk));
        const float x0f = floorf(ix), y0f = floorf(iy);
        const float wx = ix - x0f,    wy = iy - y0f;
        const int x0 = (int)x0f, y0 = (int)y0f;
        const int x1 = x0 + 1,   y1 = y0 + 1;
        const bool vx0 = (x0 >= 0) && (x0 < W_);
        const bool vx1 = (x1 >= 0) && (x1 < W_);
        const bool vy0 = (y0 >= 0) && (y0 < H_);
        const bool vy1 = (y1 >= 0) && (y1 < H_);
        const int cx0 = min(max(x0, 0), W_ - 1);
        const int cx1 = min(max(x1, 0), W_ - 1);
        const int cy0 = min(max(y0, 0), H_ - 1);
        const int cy1 = min(max(y1, 0), H_ - 1);
        const float m = inreg ? 1.0f : 0.0f;
        const float q0 = (1.0f - wx) * (1.0f - wy) * ((vx0 && vy0) ? m : 0.0f);
        const float q1 = wx * (1.0f - wy)          * ((vx1 && vy0) ? m : 0.0f);
        const float q2 = (1.0f - wx) * wy          * ((vx0 && vy1) ? m : 0.0f);
        const float q3 = wx * wy                   * ((vx1 && vy1) ? m : 0.0f);

        // fold x0/x1 taps of each source row into one 8B pair load at xs
        const int xs = min(max(x0, 0), W_ - 2);
        oA[it] = cy0 * W_ + xs;
        oB[it] = cy1 * W_ + xs;
        aAx[it] = (cx0 == xs     ? q0 : 0.0f) + (cx1 == xs     ? q1 : 0.0f);
        aAy[it] = (cx0 == xs + 1 ? q0 : 0.0f) + (cx1 == xs + 1 ? q1 : 0.0f);
        aBx[it] = (cx0 == xs     ? q2 : 0.0f) + (cx1 == xs     ? q3 : 0.0f);
        aBy[it] = (cx0 == xs + 1 ? q2 : 0.0f) + (cx1 == xs + 1 ? q3 : 0.0f);
        sidx[it] = (p < NPOS) ? (pr * REG + pc) : -1;
    }

    // pass 1a: LOAD phase — distinct payload registers per tap pair so all
    // 10 predicated loads issue before any s_waitcnt (latency collapsed
    // into ~1 round-trip). All indices compile-time (no scratch).
    float2u vA[PPT], vB[PPT];
    #pragma unroll
    for (int it = 0; it < PPT; ++it) {
        vA[it] = (float2u){0.f, 0.f};
        vB[it] = (float2u){0.f, 0.f};
        if (aAx[it] != 0.f || aAy[it] != 0.f)
            vA[it] = *reinterpret_cast<const float2u*>(img + oA[it]);
        if (aBx[it] != 0.f || aBy[it] != 0.f)
            vB[it] = *reinterpret_cast<const float2u*>(img + oB[it]);
    }

    // pass 1b: combine + LDS write
    #pragma unroll
    for (int it = 0; it < PPT; ++it) {
        const float s = aAx[it] * vA[it].x + aAy[it] * vA[it].y
                      + aBx[it] * vB[it].x + aBy[it] * vB[it].y;
        if (sidx[it] >= 0) lds[sidx[it]] = s;
    }
    __syncthreads();

    // pass 2: constant-weight 2x2 blend from LDS, 4 outputs per thread
    const float* Lr0 = lds + rr * REG + cg;
    const float* Lr1 = Lr0 + REG;
    const float l0 = Lr0[0], l1 = Lr0[1], l2 = Lr0[2], l3 = Lr0[3], l4 = Lr0[4];
    const float m0 = Lr1[0], m1 = Lr1[1], m2 = Lr1[2], m3 = Lr1[3], m4 = Lr1[4];
    float4e v;
    v.x = w00 * l0 + w01 * l1 + w10 * m0 + w11 * m1;
    v.y = w00 * l1 + w01 * l2 + w10 * m1 + w11 * m2;
    v.z = w00 * l2 + w01 * l3 + w10 * m2 + w11 * m3;
    v.w = w00 * l3 + w01 * l4 + w10 * m3 + w11 * m4;
    __builtin_nontemporal_store(v, reinterpret_cast<float4e*>(o + off));
}

extern "C" void kernel_launch(void* const* d_in, const int* in_sizes, int n_in,
                              void* d_out, int out_size, void* d_ws, size_t ws_size,
                              hipStream_t stream) {
    const float* bevs   = (const float*)d_in[0];
    const float* tm     = (const float*)d_in[1];
    const int*   nat    = (const int*)d_in[2];
    const int*   center = (const int*)d_in[4];
    float* out = (float*)d_out;

    dim3 grid(NBLK);
    dim3 block(NT);
    fafmimo_warp_kernel<<<grid, block, 0, stream>>>(bevs, tm, nat, center, out);
}